// Round 5
// baseline (328.374 us; speedup 1.0000x reference)
//
#include <hip/hip_runtime.h>
#include <hip/hip_bf16.h>

#define IN_FEAT 128
#define N_HEADS 4
#define OUT_FEAT 16
#define HF 64  // N_HEADS * OUT_FEAT
#define NEG_SLOPE 0.2f

typedef __hip_bfloat16 bf16;
typedef __attribute__((ext_vector_type(8))) short short8;
typedef __attribute__((ext_vector_type(4))) float f32x4;

__device__ inline unsigned short f2b(float f) {
  bf16 b = __float2bfloat16(f);
  return *(unsigned short*)&b;
}
__device__ inline float b2f(unsigned short u) {
  return __uint_as_float((unsigned)u << 16);
}

// ---------------------------------------------------------------------------
// Kernel 1: h = x @ W via bf16 MFMA (as round 4) + FUSED dst histogram.
// Block = 256 thr = 4 waves = 64 nodes; 16 mfma_f32_16x16x32_bf16 per wave.
// After the tile work each thread grid-strides over edges doing the
// counts histogram (independent of tile work; overlaps with other blocks).
// ---------------------------------------------------------------------------
__global__ __launch_bounds__(256) void k_gemm(
    const float* __restrict__ x, const float* __restrict__ W,
    const float* __restrict__ a, unsigned short* __restrict__ h16,
    float* __restrict__ e_src, float* __restrict__ e_dst,
    const int* __restrict__ dst, int* __restrict__ counts,
    int n_nodes, int n_edges) {
  __shared__ unsigned short xs[64][136];
  __shared__ unsigned short wt[64][136];
  __shared__ unsigned short sh[64][68];
  const int t = threadIdx.x;
  const int nb = blockIdx.x * 64;
  const int lane = t & 63;
  const int w = t >> 6;

  const float4* x4 = (const float4*)x;
  for (int i = t; i < 64 * 32; i += 256) {
    int n = i >> 5, k4 = i & 31;
    int gn = nb + n;
    float4 v = (gn < n_nodes) ? x4[(size_t)gn * 32 + k4]
                              : make_float4(0.f, 0.f, 0.f, 0.f);
    ushort4 u;
    u.x = f2b(v.x); u.y = f2b(v.y); u.z = f2b(v.z); u.w = f2b(v.w);
    *(ushort4*)&xs[n][k4 * 4] = u;
  }
  for (int i = t; i < IN_FEAT * HF; i += 256) {
    int k = i >> 6, c = i & 63;
    wt[c][k] = f2b(W[i]);
  }
  __syncthreads();

  const int m = lane & 15;
  const int q = lane >> 4;
  f32x4 acc[4];
#pragma unroll
  for (int nt = 0; nt < 4; ++nt) acc[nt] = (f32x4){0.f, 0.f, 0.f, 0.f};

#pragma unroll
  for (int kc = 0; kc < 4; ++kc) {
    short8 af = *(const short8*)&xs[w * 16 + m][kc * 32 + q * 8];
#pragma unroll
    for (int nt = 0; nt < 4; ++nt) {
      short8 bfr = *(const short8*)&wt[nt * 16 + m][kc * 32 + q * 8];
      acc[nt] = __builtin_amdgcn_mfma_f32_16x16x32_bf16(af, bfr, acc[nt], 0, 0, 0);
    }
  }

#pragma unroll
  for (int nt = 0; nt < 4; ++nt)
#pragma unroll
    for (int r = 0; r < 4; ++r)
      sh[w * 16 + q * 4 + r][nt * 16 + m] = f2b(acc[nt][r]);
  __syncthreads();

  {
    int n = t >> 2, hd = t & 3;
    int gn = nb + n;
    if (gn < n_nodes) {
      float es = 0.f, ed = 0.f;
#pragma unroll
      for (int f = 0; f < OUT_FEAT; ++f) {
        float hv = b2f(sh[n][hd * 16 + f]);
        es = fmaf(hv, a[hd * 2 * OUT_FEAT + f], es);
        ed = fmaf(hv, a[hd * 2 * OUT_FEAT + OUT_FEAT + f], ed);
      }
      e_src[gn * N_HEADS + hd] = es;
      e_dst[gn * N_HEADS + hd] = ed;
    }
  }

  for (int i = t; i < 64 * 16; i += 256) {
    int n = i >> 4, c4 = (i & 15) * 4;
    int gn = nb + n;
    if (gn < n_nodes) {
      ushort4 v;
      v.x = sh[n][c4 + 0]; v.y = sh[n][c4 + 1];
      v.z = sh[n][c4 + 2]; v.w = sh[n][c4 + 3];
      *(ushort4*)(h16 + (size_t)gn * HF + c4) = v;
    }
  }

  // Fused histogram: grid-stride over edges.
  const int stride = gridDim.x * 256;
  for (int e = blockIdx.x * 256 + t; e < n_edges; e += stride)
    atomicAdd(&counts[dst[e]], 1);
}

// ---------------------------------------------------------------------------
// Single-block exclusive scan of counts[n] -> offsets[n+1], cursor[n].
// 1024 threads, contiguous 49-element chunk per thread (L1-sequential),
// Hillis-Steele block scan of the 1024 chunk sums.
// ---------------------------------------------------------------------------
__global__ __launch_bounds__(1024) void k_scan(
    const int* __restrict__ counts, int* __restrict__ offsets,
    int* __restrict__ cursor, int n, int n_edges) {
  __shared__ int s[1024];
  const int t = threadIdx.x;
  const int per = (n + 1023) / 1024;  // 49 for n=50000
  const int base = t * per;
  int sum = 0;
  for (int i = 0; i < per; ++i) {
    int idx = base + i;
    if (idx < n) sum += counts[idx];
  }
  s[t] = sum;
  __syncthreads();
  for (int off = 1; off < 1024; off <<= 1) {
    int v = (t >= off) ? s[t - off] : 0;
    __syncthreads();
    s[t] += v;
    __syncthreads();
  }
  int run = s[t] - sum;  // exclusive prefix of this chunk
  for (int i = 0; i < per; ++i) {
    int idx = base + i;
    if (idx < n) {
      offsets[idx] = run;
      cursor[idx] = run;
      run += counts[idx];
    }
  }
  if (t == 0) offsets[n] = n_edges;
}

// ---------------------------------------------------------------------------
// Reorder + FUSED per-edge softmax: one thread per edge.
// Gathers e_src[s]/e_dst[d] (16B each, L2-resident tables), computes the
// 4-head softmax ONCE, packs alpha as 4x bf16 into one u64, scatters
// sorted_src (4B) + alpha8 (8B) to the CSR position.
// ---------------------------------------------------------------------------
__global__ __launch_bounds__(256) void k_reorder(
    const int* __restrict__ src, const int* __restrict__ dst,
    const float* __restrict__ e_src, const float* __restrict__ e_dst,
    int* __restrict__ cursor, int* __restrict__ sorted_src,
    unsigned long long* __restrict__ alpha8, int n_edges) {
  int e = blockIdx.x * 256 + threadIdx.x;
  if (e >= n_edges) return;
  int s = src[e], d = dst[e];
  float4 es = ((const float4*)e_src)[s];
  float4 ed = ((const float4*)e_dst)[d];
  float v0 = es.x + ed.x, v1 = es.y + ed.y, v2 = es.z + ed.z, v3 = es.w + ed.w;
  v0 = (v0 > 0.f) ? v0 : NEG_SLOPE * v0;
  v1 = (v1 > 0.f) ? v1 : NEG_SLOPE * v1;
  v2 = (v2 > 0.f) ? v2 : NEG_SLOPE * v2;
  v3 = (v3 > 0.f) ? v3 : NEG_SLOPE * v3;
  float m = fmaxf(fmaxf(v0, v1), fmaxf(v2, v3));
  float e0 = __expf(v0 - m), e1 = __expf(v1 - m);
  float e2 = __expf(v2 - m), e3 = __expf(v3 - m);
  float inv = 1.f / (e0 + e1 + e2 + e3);
  unsigned long long pack =
      (unsigned long long)f2b(e0 * inv) |
      ((unsigned long long)f2b(e1 * inv) << 16) |
      ((unsigned long long)f2b(e2 * inv) << 32) |
      ((unsigned long long)f2b(e3 * inv) << 48);
  int pos = atomicAdd(&cursor[d], 1);
  sorted_src[pos] = s;
  alpha8[pos] = pack;
}

// ---------------------------------------------------------------------------
// Gather: one wave per dst node, lane = feature. Lean inner loop:
// per edge ~9 VALU (u64 alpha load, shift-extract, ushort h gather, fma),
// unrolled x8 -> 8 independent load chains for MLP.
// ---------------------------------------------------------------------------
__global__ __launch_bounds__(256) void k_gather(
    const int* __restrict__ sorted_src,
    const unsigned long long* __restrict__ alpha8,
    const int* __restrict__ offsets, const unsigned short* __restrict__ h16,
    float* __restrict__ out, int n_nodes) {
  int gid = blockIdx.x * 256 + threadIdx.x;
  int d = gid >> 6;
  int c = gid & 63;
  if (d >= n_nodes) return;
  int beg = offsets[d];
  int end = offsets[d + 1];
  unsigned shamt = (unsigned)(c >> 4) * 16;
  float acc = 0.f;
  int j = beg;
  for (; j + 8 <= end; j += 8) {
    int s[8];
    unsigned long long au[8];
    float hv[8];
#pragma unroll
    for (int k = 0; k < 8; ++k) s[k] = sorted_src[j + k];
#pragma unroll
    for (int k = 0; k < 8; ++k) au[k] = alpha8[j + k];
#pragma unroll
    for (int k = 0; k < 8; ++k) hv[k] = b2f(h16[(size_t)s[k] * HF + c]);
#pragma unroll
    for (int k = 0; k < 8; ++k) {
      float al = __uint_as_float(((unsigned)(au[k] >> shamt)) << 16);
      acc = fmaf(al, hv[k], acc);
    }
  }
  for (; j < end; ++j) {
    int s = sorted_src[j];
    unsigned long long au = alpha8[j];
    float al = __uint_as_float(((unsigned)(au >> shamt)) << 16);
    acc = fmaf(al, b2f(h16[(size_t)s * HF + c]), acc);
  }
  out[(size_t)d * HF + c] = acc;
}

extern "C" void kernel_launch(void* const* d_in, const int* in_sizes, int n_in,
                              void* d_out, int out_size, void* d_ws, size_t ws_size,
                              hipStream_t stream) {
  const float* x = (const float*)d_in[0];
  const int* ei = (const int*)d_in[1];
  const float* W = (const float*)d_in[2];
  const float* a = (const float*)d_in[3];
  float* out = (float*)d_out;

  const int n_nodes = in_sizes[0] / IN_FEAT;   // 50000
  const int n_edges = in_sizes[1] / 2;         // 800000
  const int* src = ei;
  const int* dst = ei + n_edges;

  char* ws = (char*)d_ws;
  size_t off = 0;
  unsigned short* h16 = (unsigned short*)(ws + off); off += (size_t)n_nodes * HF * 2;   // 6.4 MB
  unsigned long long* alpha8 = (unsigned long long*)(ws + off); off += (size_t)n_edges * 8; // 6.4 MB
  float* e_src = (float*)(ws + off);      off += (size_t)n_nodes * N_HEADS * 4;         // 0.8 MB
  float* e_dst = (float*)(ws + off);      off += (size_t)n_nodes * N_HEADS * 4;         // 0.8 MB
  int* sorted_src = (int*)(ws + off);     off += (size_t)n_edges * 4;                   // 3.2 MB
  int* counts = (int*)(ws + off);         off += ((size_t)n_nodes + 16) * 4;
  int* offsets = (int*)(ws + off);        off += ((size_t)n_nodes + 16) * 4;
  int* cursor = (int*)(ws + off);         off += ((size_t)n_nodes + 16) * 4;

  const int nb_edges = (n_edges + 255) / 256;

  hipMemsetAsync(counts, 0, (size_t)n_nodes * 4, stream);
  k_gemm<<<(n_nodes + 63) / 64, 256, 0, stream>>>(
      x, W, a, h16, e_src, e_dst, dst, counts, n_nodes, n_edges);
  k_scan<<<1, 1024, 0, stream>>>(counts, offsets, cursor, n_nodes, n_edges);
  k_reorder<<<nb_edges, 256, 0, stream>>>(
      src, dst, e_src, e_dst, cursor, sorted_src, alpha8, n_edges);
  k_gather<<<(n_nodes * 64 + 255) / 256, 256, 0, stream>>>(
      sorted_src, alpha8, offsets, h16, out, n_nodes);
}

// Round 6
// 211.164 us; speedup vs baseline: 1.5551x; 1.5551x over previous
//
#include <hip/hip_runtime.h>
#include <hip/hip_bf16.h>

#define IN_FEAT 128
#define N_HEADS 4
#define OUT_FEAT 16
#define HF 64  // N_HEADS * OUT_FEAT
#define NEG_SLOPE 0.2f

typedef __hip_bfloat16 bf16;
typedef __attribute__((ext_vector_type(8))) short short8;
typedef __attribute__((ext_vector_type(4))) float f32x4;

__device__ inline unsigned short f2b(float f) {
  bf16 b = __float2bfloat16(f);
  return *(unsigned short*)&b;
}
__device__ inline float b2f(unsigned short u) {
  return __uint_as_float((unsigned)u << 16);
}

// ---------------------------------------------------------------------------
// Kernel 1: h = x @ W via bf16 MFMA + FUSED dst histogram.
// Block = 256 thr = 4 waves = 64 nodes; 16 mfma_f32_16x16x32_bf16 per wave.
// ---------------------------------------------------------------------------
__global__ __launch_bounds__(256) void k_gemm(
    const float* __restrict__ x, const float* __restrict__ W,
    const float* __restrict__ a, unsigned short* __restrict__ h16,
    float* __restrict__ e_src, float* __restrict__ e_dst,
    const int* __restrict__ dst, int* __restrict__ counts,
    int n_nodes, int n_edges) {
  __shared__ unsigned short xs[64][136];
  __shared__ unsigned short wt[64][136];
  __shared__ unsigned short sh[64][68];
  const int t = threadIdx.x;
  const int nb = blockIdx.x * 64;
  const int lane = t & 63;
  const int w = t >> 6;

  const float4* x4 = (const float4*)x;
  for (int i = t; i < 64 * 32; i += 256) {
    int n = i >> 5, k4 = i & 31;
    int gn = nb + n;
    float4 v = (gn < n_nodes) ? x4[(size_t)gn * 32 + k4]
                              : make_float4(0.f, 0.f, 0.f, 0.f);
    ushort4 u;
    u.x = f2b(v.x); u.y = f2b(v.y); u.z = f2b(v.z); u.w = f2b(v.w);
    *(ushort4*)&xs[n][k4 * 4] = u;
  }
  for (int i = t; i < IN_FEAT * HF; i += 256) {
    int k = i >> 6, c = i & 63;
    wt[c][k] = f2b(W[i]);
  }
  __syncthreads();

  const int m = lane & 15;
  const int q = lane >> 4;
  f32x4 acc[4];
#pragma unroll
  for (int nt = 0; nt < 4; ++nt) acc[nt] = (f32x4){0.f, 0.f, 0.f, 0.f};

#pragma unroll
  for (int kc = 0; kc < 4; ++kc) {
    short8 af = *(const short8*)&xs[w * 16 + m][kc * 32 + q * 8];
#pragma unroll
    for (int nt = 0; nt < 4; ++nt) {
      short8 bfr = *(const short8*)&wt[nt * 16 + m][kc * 32 + q * 8];
      acc[nt] = __builtin_amdgcn_mfma_f32_16x16x32_bf16(af, bfr, acc[nt], 0, 0, 0);
    }
  }

#pragma unroll
  for (int nt = 0; nt < 4; ++nt)
#pragma unroll
    for (int r = 0; r < 4; ++r)
      sh[w * 16 + q * 4 + r][nt * 16 + m] = f2b(acc[nt][r]);
  __syncthreads();

  {
    int n = t >> 2, hd = t & 3;
    int gn = nb + n;
    if (gn < n_nodes) {
      float es = 0.f, ed = 0.f;
#pragma unroll
      for (int f = 0; f < OUT_FEAT; ++f) {
        float hv = b2f(sh[n][hd * 16 + f]);
        es = fmaf(hv, a[hd * 2 * OUT_FEAT + f], es);
        ed = fmaf(hv, a[hd * 2 * OUT_FEAT + OUT_FEAT + f], ed);
      }
      e_src[gn * N_HEADS + hd] = es;
      e_dst[gn * N_HEADS + hd] = ed;
    }
  }

  for (int i = t; i < 64 * 16; i += 256) {
    int n = i >> 4, c4 = (i & 15) * 4;
    int gn = nb + n;
    if (gn < n_nodes) {
      ushort4 v;
      v.x = sh[n][c4 + 0]; v.y = sh[n][c4 + 1];
      v.z = sh[n][c4 + 2]; v.w = sh[n][c4 + 3];
      *(ushort4*)(h16 + (size_t)gn * HF + c4) = v;
    }
  }

  // Fused histogram: grid-stride over edges.
  const int stride = gridDim.x * 256;
  for (int e = blockIdx.x * 256 + t; e < n_edges; e += stride)
    atomicAdd(&counts[dst[e]], 1);
}

// ---------------------------------------------------------------------------
// 3-kernel coalesced scan (round-4 proven): tile sums -> scan sums -> apply.
// ---------------------------------------------------------------------------
__global__ __launch_bounds__(256) void k_scan1(
    const int* __restrict__ counts, int* __restrict__ partial, int n) {
  __shared__ int s[256];
  int t = threadIdx.x;
  int i = blockIdx.x * 256 + t;
  s[t] = (i < n) ? counts[i] : 0;
  __syncthreads();
  for (int off = 128; off > 0; off >>= 1) {
    if (t < off) s[t] += s[t + off];
    __syncthreads();
  }
  if (t == 0) partial[blockIdx.x] = s[0];
}

__global__ __launch_bounds__(256) void k_scan2(int* __restrict__ partial, int nb) {
  __shared__ int s[256];
  int t = threadIdx.x;
  s[t] = (t < nb) ? partial[t] : 0;
  __syncthreads();
  for (int off = 1; off < 256; off <<= 1) {
    int v = (t >= off) ? s[t - off] : 0;
    __syncthreads();
    s[t] += v;
    __syncthreads();
  }
  if (t < nb) partial[t] = (t == 0) ? 0 : s[t - 1];
}

__global__ __launch_bounds__(256) void k_scan3(
    const int* __restrict__ counts, const int* __restrict__ partial,
    int* __restrict__ offsets, int* __restrict__ cursor, int n, int n_edges) {
  __shared__ int s[256];
  int t = threadIdx.x;
  int i = blockIdx.x * 256 + t;
  int v = (i < n) ? counts[i] : 0;
  s[t] = v;
  __syncthreads();
  for (int off = 1; off < 256; off <<= 1) {
    int u = (t >= off) ? s[t - off] : 0;
    __syncthreads();
    s[t] += u;
    __syncthreads();
  }
  int excl = s[t] - v + partial[blockIdx.x];
  if (i < n) {
    offsets[i] = excl;
    cursor[i] = excl;
  }
  if (i == 0) offsets[n] = n_edges;
}

// ---------------------------------------------------------------------------
// Reorder + per-edge softmax (computed once), alpha packed as 4x bf16 (u64).
// ---------------------------------------------------------------------------
__global__ __launch_bounds__(256) void k_reorder(
    const int* __restrict__ src, const int* __restrict__ dst,
    const float* __restrict__ e_src, const float* __restrict__ e_dst,
    int* __restrict__ cursor, int* __restrict__ sorted_src,
    unsigned long long* __restrict__ alpha8, int n_edges) {
  int e = blockIdx.x * 256 + threadIdx.x;
  if (e >= n_edges) return;
  int s = src[e], d = dst[e];
  float4 es = ((const float4*)e_src)[s];
  float4 ed = ((const float4*)e_dst)[d];
  float v0 = es.x + ed.x, v1 = es.y + ed.y, v2 = es.z + ed.z, v3 = es.w + ed.w;
  v0 = (v0 > 0.f) ? v0 : NEG_SLOPE * v0;
  v1 = (v1 > 0.f) ? v1 : NEG_SLOPE * v1;
  v2 = (v2 > 0.f) ? v2 : NEG_SLOPE * v2;
  v3 = (v3 > 0.f) ? v3 : NEG_SLOPE * v3;
  float m = fmaxf(fmaxf(v0, v1), fmaxf(v2, v3));
  float e0 = __expf(v0 - m), e1 = __expf(v1 - m);
  float e2 = __expf(v2 - m), e3 = __expf(v3 - m);
  float inv = 1.f / (e0 + e1 + e2 + e3);
  unsigned long long pack =
      (unsigned long long)f2b(e0 * inv) |
      ((unsigned long long)f2b(e1 * inv) << 16) |
      ((unsigned long long)f2b(e2 * inv) << 32) |
      ((unsigned long long)f2b(e3 * inv) << 48);
  int pos = atomicAdd(&cursor[d], 1);
  sorted_src[pos] = s;
  alpha8[pos] = pack;
}

// ---------------------------------------------------------------------------
// Gather: one wave per dst node, lane = feature. Lean loop, unroll x8.
// ---------------------------------------------------------------------------
__global__ __launch_bounds__(256) void k_gather(
    const int* __restrict__ sorted_src,
    const unsigned long long* __restrict__ alpha8,
    const int* __restrict__ offsets, const unsigned short* __restrict__ h16,
    float* __restrict__ out, int n_nodes) {
  int gid = blockIdx.x * 256 + threadIdx.x;
  int d = gid >> 6;
  int c = gid & 63;
  if (d >= n_nodes) return;
  int beg = offsets[d];
  int end = offsets[d + 1];
  unsigned shamt = (unsigned)(c >> 4) * 16;
  float acc = 0.f;
  int j = beg;
  for (; j + 8 <= end; j += 8) {
    int s[8];
    unsigned long long au[8];
    float hv[8];
#pragma unroll
    for (int k = 0; k < 8; ++k) s[k] = sorted_src[j + k];
#pragma unroll
    for (int k = 0; k < 8; ++k) au[k] = alpha8[j + k];
#pragma unroll
    for (int k = 0; k < 8; ++k) hv[k] = b2f(h16[(size_t)s[k] * HF + c]);
#pragma unroll
    for (int k = 0; k < 8; ++k) {
      float al = __uint_as_float(((unsigned)(au[k] >> shamt)) << 16);
      acc = fmaf(al, hv[k], acc);
    }
  }
  for (; j < end; ++j) {
    int s = sorted_src[j];
    unsigned long long au = alpha8[j];
    float al = __uint_as_float(((unsigned)(au >> shamt)) << 16);
    acc = fmaf(al, b2f(h16[(size_t)s * HF + c]), acc);
  }
  out[(size_t)d * HF + c] = acc;
}

extern "C" void kernel_launch(void* const* d_in, const int* in_sizes, int n_in,
                              void* d_out, int out_size, void* d_ws, size_t ws_size,
                              hipStream_t stream) {
  const float* x = (const float*)d_in[0];
  const int* ei = (const int*)d_in[1];
  const float* W = (const float*)d_in[2];
  const float* a = (const float*)d_in[3];
  float* out = (float*)d_out;

  const int n_nodes = in_sizes[0] / IN_FEAT;   // 50000
  const int n_edges = in_sizes[1] / 2;         // 800000
  const int* src = ei;
  const int* dst = ei + n_edges;

  char* ws = (char*)d_ws;
  size_t off = 0;
  unsigned short* h16 = (unsigned short*)(ws + off); off += (size_t)n_nodes * HF * 2;   // 6.4 MB
  unsigned long long* alpha8 = (unsigned long long*)(ws + off); off += (size_t)n_edges * 8; // 6.4 MB
  float* e_src = (float*)(ws + off);      off += (size_t)n_nodes * N_HEADS * 4;         // 0.8 MB
  float* e_dst = (float*)(ws + off);      off += (size_t)n_nodes * N_HEADS * 4;         // 0.8 MB
  int* sorted_src = (int*)(ws + off);     off += (size_t)n_edges * 4;                   // 3.2 MB
  int* counts = (int*)(ws + off);         off += ((size_t)n_nodes + 16) * 4;
  int* offsets = (int*)(ws + off);        off += ((size_t)n_nodes + 16) * 4;
  int* cursor = (int*)(ws + off);         off += ((size_t)n_nodes + 16) * 4;
  int* partial = (int*)(ws + off);        off += 256 * 4;

  const int nb_nodes = (n_nodes + 255) / 256;  // 196 <= 256 (k_scan2 limit)
  const int nb_edges = (n_edges + 255) / 256;

  hipMemsetAsync(counts, 0, (size_t)n_nodes * 4, stream);
  k_gemm<<<(n_nodes + 63) / 64, 256, 0, stream>>>(
      x, W, a, h16, e_src, e_dst, dst, counts, n_nodes, n_edges);
  k_scan1<<<nb_nodes, 256, 0, stream>>>(counts, partial, n_nodes);
  k_scan2<<<1, 256, 0, stream>>>(partial, nb_nodes);
  k_scan3<<<nb_nodes, 256, 0, stream>>>(counts, partial, offsets, cursor, n_nodes, n_edges);
  k_reorder<<<nb_edges, 256, 0, stream>>>(
      src, dst, e_src, e_dst, cursor, sorted_src, alpha8, n_edges);
  k_gather<<<(n_nodes * 64 + 255) / 256, 256, 0, stream>>>(
      sorted_src, alpha8, offsets, h16, out, n_nodes);
}